// Round 8
// baseline (244.292 us; speedup 1.0000x reference)
//
#include <hip/hip_runtime.h>
#include <hip/hip_bf16.h>
#include <math.h>

// Problem constants (fixed by setup_inputs)
#define B_    16
#define CIN   512
#define SEQ   1024
#define NH    4
#define DK    128
#define OUT3  1536
#define NT    16                      // j-tiles in attn (SEQ/64)
#define SCALE 0.08838834764831845f    // 1/sqrt(128)
// exp2-domain softmax constants: exp(s*SCALE - CSHIFT) == exp2(s*SCALE_L2E - CSHIFT_L2E)
#define SCALE_L2E  0.12751743360f     // SCALE * log2(e)
#define CSHIFT_L2E 11.54156032711f    // 8 * log2(e)

typedef __attribute__((ext_vector_type(8))) __bf16 bf16x8;   // MFMA A/B frag
typedef __attribute__((ext_vector_type(4))) float f32x4;     // MFMA C/D frag

#define MFMA(a, b, c) __builtin_amdgcn_mfma_f32_16x16x32_bf16((a), (b), (c), 0, 0, 0)

__device__ __forceinline__ ushort f2bf(float f) {
    __hip_bfloat16 h = __float2bfloat16(f);   // RTNE
    return *(ushort*)&h;
}
__device__ __forceinline__ uint pk2(float a, float b) {
    return (uint)f2bf(a) | ((uint)f2bf(b) << 16);
}
// async global->LDS, 16B per lane; lds dest is wave-uniform base (HW adds lane*16)
__device__ __forceinline__ void g2l16(const ushort* g, ushort* l) {
    __builtin_amdgcn_global_load_lds(
        (const __attribute__((address_space(1))) unsigned int*)g,
        (__attribute__((address_space(3))) unsigned int*)l, 16, 0, 0);
}
// T1: bijective XCD-chunked remap (nwg % 8 == 0 for all our grids)
__device__ __forceinline__ int xcdswz(int bid, int nwg) {
    return (bid & 7) * (nwg >> 3) + (bid >> 3);
}

// ---------------------------------------------------------------------------
// k0: x [B][C][seq] fp32 -> xt [B][seq][C] bf16  (LDS transpose, 64x64 tile)
// ---------------------------------------------------------------------------
__global__ __launch_bounds__(256) void transpose_cast_kernel(
    const float* __restrict__ x, ushort* __restrict__ xt)
{
    __shared__ ushort t[64 * 66];
    const int tid = threadIdx.x;
    const int i0 = blockIdx.x * 64, c0 = blockIdx.y * 64, b = blockIdx.z;

    #pragma unroll
    for (int l = 0; l < 4; ++l) {
        int idx = tid + l * 256;
        int c = idx >> 4, i4 = (idx & 15) << 2;
        float4 v = *(const float4*)&x[((size_t)b * CIN + c0 + c) * SEQ + i0 + i4];
        t[(i4 + 0) * 66 + c] = f2bf(v.x);
        t[(i4 + 1) * 66 + c] = f2bf(v.y);
        t[(i4 + 2) * 66 + c] = f2bf(v.z);
        t[(i4 + 3) * 66 + c] = f2bf(v.w);
    }
    __syncthreads();
    #pragma unroll
    for (int l = 0; l < 4; ++l) {
        int idx = tid + l * 256;
        int i = idx >> 4, c4 = (idx & 15) << 2;
        uint2 p;
        p.x = *(const uint*)&t[i * 66 + c4];
        p.y = *(const uint*)&t[i * 66 + c4 + 2];
        *(uint2*)&xt[((size_t)b * SEQ + i0 + i) * CIN + c0 + c4] = p;
    }
}

// ---------------------------------------------------------------------------
// prep: fp32 -> bf16 cast for BOTH w_proj (196608 quads) and w_out (65536)
// ---------------------------------------------------------------------------
__global__ __launch_bounds__(256) void cast_kernel(
    const float* __restrict__ wp, const float* __restrict__ wo,
    ushort* __restrict__ dwp, ushort* __restrict__ dwo)
{
    int idx = blockIdx.x * 256 + threadIdx.x;     // grid 1024 -> 262144 quads
    if (idx < 196608) {
        float4 v = *(const float4*)&wp[(size_t)idx * 4];
        uint2 p; p.x = pk2(v.x, v.y); p.y = pk2(v.z, v.w);
        *(uint2*)&dwp[(size_t)idx * 4] = p;
    } else {
        int j = idx - 196608;
        float4 v = *(const float4*)&wo[(size_t)j * 4];
        uint2 p; p.x = pk2(v.x, v.y); p.y = pk2(v.z, v.w);
        *(uint2*)&dwo[(size_t)j * 4] = p;
    }
}

// ---------------------------------------------------------------------------
// k1: QKV projection.  D[o][i] = sum_c Wbf[o][c] * xt[i][c]  (+bias)
// 128x128 block, BK=32, double-buffered global_load_lds prefetch-before-compute.
// q,k -> [bh][seq][128]; v -> TRANSPOSED [bh][128][seq].
// ---------------------------------------------------------------------------
__global__ __launch_bounds__(256) void qkv_kernel(
    const ushort* __restrict__ wbf, const float* __restrict__ bias,
    const ushort* __restrict__ xt,
    ushort* __restrict__ qb, ushort* __restrict__ kb, ushort* __restrict__ vtb)
{
    __shared__ __attribute__((aligned(16))) ushort lds_a0[128 * 32];
    __shared__ __attribute__((aligned(16))) ushort lds_a1[128 * 32];
    __shared__ __attribute__((aligned(16))) ushort lds_b0[128 * 32];
    __shared__ __attribute__((aligned(16))) ushort lds_b1[128 * 32];
    const int tid = threadIdx.x;
    const int lane = tid & 63, wv = tid >> 6;
    const int l15 = lane & 15, l4 = lane >> 4;
    const int wm = wv >> 1, wn = wv & 1;
    const int swz = xcdswz(blockIdx.x, 1536);
    const int o0 = (swz % 12) * 128;
    const int i0 = ((swz / 12) & 7) * 128;
    const int b  = swz / 96;

    auto stage = [&](int c0, ushort* la, ushort* lb) {
        #pragma unroll
        for (int l = 0; l < 2; ++l) {
            int chunk = l * 256 + tid;
            int row = chunk >> 2, c = chunk & 3;
            g2l16(&wbf[(size_t)(o0 + row) * CIN + c0 + (c << 3)],
                  &la[(size_t)(l * 256 + wv * 64) * 8]);
        }
        #pragma unroll
        for (int l = 0; l < 2; ++l) {
            int chunk = l * 256 + tid;
            int row = chunk >> 2, c = chunk & 3;
            g2l16(&xt[((size_t)b * SEQ + i0 + row) * CIN + c0 + (c << 3)],
                  &lb[(size_t)(l * 256 + wv * 64) * 8]);
        }
    };

    f32x4 acc[4][4] = {};
    stage(0, lds_a0, lds_b0);
    __syncthreads();
    for (int it = 0; it < CIN / 32; ++it) {
        const ushort* la = (it & 1) ? lds_a1 : lds_a0;
        const ushort* lb = (it & 1) ? lds_b1 : lds_b0;
        if (it + 1 < CIN / 32)
            stage((it + 1) * 32, (it & 1) ? lds_a0 : lds_a1,
                                 (it & 1) ? lds_b0 : lds_b1);
        bf16x8 af[4], bfv[4];
        #pragma unroll
        for (int m = 0; m < 4; ++m)
            af[m] = *(const bf16x8*)&la[(wm * 64 + m * 16 + l15) * 32 + (l4 << 3)];
        #pragma unroll
        for (int n = 0; n < 4; ++n)
            bfv[n] = *(const bf16x8*)&lb[(wn * 64 + n * 16 + l15) * 32 + (l4 << 3)];
        #pragma unroll
        for (int m = 0; m < 4; ++m)
            #pragma unroll
            for (int n = 0; n < 4; ++n)
                acc[m][n] = MFMA(af[m], bfv[n], acc[m][n]);
        __syncthreads();
    }
    // epilogue: o-block (128-aligned) sits in exactly one (head, q/k/v) chunk
    const int h = o0 / 384, which = (o0 % 384) / 128;
    const int bh = b * NH + h;
    #pragma unroll
    for (int m = 0; m < 4; ++m) {
        const int d0 = wm * 64 + m * 16 + (l4 << 2);
        float bia[4];
        #pragma unroll
        for (int r = 0; r < 4; ++r) bia[r] = bias[o0 + d0 + r];
        #pragma unroll
        for (int n = 0; n < 4; ++n) {
            const int i = i0 + wn * 64 + n * 16 + l15;
            float v0 = acc[m][n][0] + bia[0], v1 = acc[m][n][1] + bia[1];
            float v2 = acc[m][n][2] + bia[2], v3 = acc[m][n][3] + bia[3];
            if (which == 2) {                     // v: transposed store [bh][d][i]
                vtb[((size_t)bh * DK + d0 + 0) * SEQ + i] = f2bf(v0);
                vtb[((size_t)bh * DK + d0 + 1) * SEQ + i] = f2bf(v1);
                vtb[((size_t)bh * DK + d0 + 2) * SEQ + i] = f2bf(v2);
                vtb[((size_t)bh * DK + d0 + 3) * SEQ + i] = f2bf(v3);
            } else {                              // q/k: [bh][i][d], 8B packed
                ushort* dst = (which == 0) ? qb : kb;
                uint2 p; p.x = pk2(v0, v1); p.y = pk2(v2, v3);
                *(uint2*)&dst[((size_t)bh * SEQ + i) * DK + d0] = p;
            }
        }
    }
}

// ---------------------------------------------------------------------------
// k2: column-softmax stats via S^T = K * Q^T  (softmax axis i in lane dim).
// exp2-domain fixed shift: cstat[j] = CSHIFT_L2E + log2(sum_i 2^(s*SCALE_L2E
// - CSHIFT_L2E)).  attn then computes P = 2^(s*SCALE_L2E - cstat) exactly.
// ---------------------------------------------------------------------------
__global__ __launch_bounds__(256) void stats_kernel(
    const ushort* __restrict__ qb, const ushort* __restrict__ kb,
    float* __restrict__ cstat)
{
    __shared__ __attribute__((aligned(16))) ushort lds_q0[64 * 128];
    __shared__ __attribute__((aligned(16))) ushort lds_q1[64 * 128];
    const int tid = threadIdx.x;
    const int lane = tid & 63, wv = tid >> 6;
    const int l15 = lane & 15, l4 = lane >> 4;
    const int swz = xcdswz(blockIdx.x, 512);
    const int bh = swz >> 3;
    const int j0 = (swz & 7) * 128 + wv * 32;
    const ushort* kbase = kb + (size_t)bh * SEQ * DK;
    const ushort* qbase = qb + (size_t)bh * SEQ * DK;

    auto stageQ = [&](int it, ushort* dst) {
        #pragma unroll
        for (int l = 0; l < 4; ++l) {
            int chunk = l * 256 + tid;
            int row = chunk >> 4, c = chunk & 15;
            g2l16(&qbase[(size_t)(it * 64 + row) * DK + ((c ^ (row & 7)) << 3)],
                  &dst[(size_t)(l * 256 + wv * 64) * 8]);
        }
    };

    bf16x8 kf[2][4];                      // wave's K rows [j32][128] in regs
    #pragma unroll
    for (int m = 0; m < 2; ++m)
        #pragma unroll
        for (int ks = 0; ks < 4; ++ks)
            kf[m][ks] = *(const bf16x8*)&kbase[(size_t)(j0 + m * 16 + l15) * DK
                                               + ks * 32 + (l4 << 3)];
    float ss[2][4] = {};

    stageQ(0, lds_q0);
    __syncthreads();
    for (int it = 0; it < SEQ / 64; ++it) {
        const ushort* lq = (it & 1) ? lds_q1 : lds_q0;
        if (it + 1 < SEQ / 64)
            stageQ(it + 1, (it & 1) ? lds_q0 : lds_q1);
        f32x4 sa0[4], sa1[4];
        __builtin_amdgcn_s_setprio(1);
        #pragma unroll
        for (int n = 0; n < 4; ++n) {
            f32x4 a0 = {}, a1 = {};
            #pragma unroll
            for (int ks = 0; ks < 4; ++ks) {
                bf16x8 bq = *(const bf16x8*)&lq[(n * 16 + l15) * 128
                                + ((((ks << 2) | l4) ^ (l15 & 7)) << 3)];
                a0 = MFMA(kf[0][ks], bq, a0);
                a1 = MFMA(kf[1][ks], bq, a1);
            }
            sa0[n] = a0; sa1[n] = a1;
        }
        __builtin_amdgcn_s_setprio(0);
        #pragma unroll
        for (int r = 0; r < 4; ++r) {
            float e0 = 0.0f, e1 = 0.0f;
            #pragma unroll
            for (int n = 0; n < 4; ++n) {
                e0 += exp2f(fmaf(sa0[n][r], SCALE_L2E, -CSHIFT_L2E));
                e1 += exp2f(fmaf(sa1[n][r], SCALE_L2E, -CSHIFT_L2E));
            }
            ss[0][r] += e0;
            ss[1][r] += e1;
        }
        __syncthreads();
    }
    #pragma unroll
    for (int m = 0; m < 2; ++m)
        #pragma unroll
        for (int r = 0; r < 4; ++r) {
            float sv = ss[m][r];
            #pragma unroll
            for (int wmask = 1; wmask < 16; wmask <<= 1)
                sv += __shfl_xor(sv, wmask, 64);
            if (l15 == 0) {
                int j = j0 + m * 16 + (l4 << 2) + r;
                cstat[(size_t)bh * SEQ + j] = CSHIFT_L2E + __log2f(sv);
            }
        }
}

// ---------------------------------------------------------------------------
// k3: attention output — T4 counted-vmcnt pipeline (no vmcnt drain at barriers).
// Full dbuf: K0/K1, V0/V1, C0/C1 (cstat staged via width-4 global_load_lds so
// no plain global load pollutes the per-wave vmcnt ledger).  Items/wave:
// stageK=4, stageC=1, stageV=4.  Steady state: every wait is vmcnt(9) =
// {next K/C pair (5) + next V (4)} allowed in flight; each buffer's landing is
// verified by counted-wait THEN s_barrier before any wave consumes it; each
// overwrite is issued only after a barrier that retires all its readers:
//   head(t):  vmcnt(9); s_barrier; issue V(t+1)        [V[(t+1)&1] freed by
//             barrier: all waves finished phaseB(t-1)]
//   phaseA(t): K[t&1],C[t&1] -> P
//   mid(t):   vmcnt(9) lgkmcnt(0); s_barrier; issue K,C(t+2)  [K/C[t&1] freed]
//   phaseB(t): V[t&1], P
// Tail: head(15)=vmcnt(4), mid(15)=vmcnt(0).
// ---------------------------------------------------------------------------
__global__ __launch_bounds__(256) void attn_kernel(
    const ushort* __restrict__ qb, const ushort* __restrict__ kb,
    const ushort* __restrict__ vtb, const float* __restrict__ cstat,
    ushort* __restrict__ resb)
{
    __shared__ __attribute__((aligned(16))) ushort K0[64 * 128], K1[64 * 128];
    __shared__ __attribute__((aligned(16))) ushort V0[128 * 64], V1[128 * 64];
    __shared__ __attribute__((aligned(16))) ushort P[64 * 64];   // dense swz16B
    __shared__ __attribute__((aligned(16))) float  C0[64], C1[64];
    const int tid = threadIdx.x;
    const int lane = tid & 63, wv = tid >> 6;
    const int l15 = lane & 15, l4 = lane >> 4;
    const int wj = wv & 1, wi = wv >> 1;
    const int swz = xcdswz(blockIdx.x, 1024);
    const int bh = swz >> 4, b = bh >> 2, h = bh & 3;
    const int i0 = (swz & 15) * 64;
    const ushort* qbase = qb + (size_t)bh * SEQ * DK;
    const ushort* kbase = kb + (size_t)bh * SEQ * DK;
    const ushort* vtbase = vtb + (size_t)bh * DK * SEQ;
    const float* cbase = cstat + (size_t)bh * SEQ;

    auto stageK = [&](ushort* dst, int jt) {
        const int j0t = jt * 64;
        #pragma unroll
        for (int l = 0; l < 4; ++l) {
            int chunk = l * 256 + tid;
            int row = chunk >> 4, c = chunk & 15;
            g2l16(&kbase[(size_t)(j0t + row) * DK + ((c ^ (row & 7)) << 3)],
                  &dst[(size_t)(l * 256 + wv * 64) * 8]);
        }
    };
    auto stageVt = [&](ushort* dst, int jt) {
        const int j0t = jt * 64;
        #pragma unroll
        for (int l = 0; l < 4; ++l) {
            int chunk = l * 256 + tid;
            int row = chunk >> 3, c = chunk & 7;
            g2l16(&vtbase[(size_t)row * SEQ + j0t + ((c ^ (row & 7)) << 3)],
                  &dst[(size_t)(l * 256 + wv * 64) * 8]);
        }
    };
    auto stageC = [&](float* dst, int jt) {     // 64 floats, width-4, all waves
        __builtin_amdgcn_global_load_lds(
            (const __attribute__((address_space(1))) unsigned int*)(cbase + jt * 64 + lane),
            (__attribute__((address_space(3))) unsigned int*)dst, 4, 0, 0);
    };

    bf16x8 qf[2][4];                      // wave's Q rows [i32][128] in regs
    #pragma unroll
    for (int n = 0; n < 2; ++n)
        #pragma unroll
        for (int ks = 0; ks < 4; ++ks)
            qf[n][ks] = *(const bf16x8*)&qbase[(size_t)(i0 + wi * 32 + n * 16 + l15) * DK
                                               + ks * 32 + (l4 << 3)];
    f32x4 oacc[2][4] = {};

    auto phaseA = [&](int jt, const ushort* Krd, const float* Crd) {
        float4 cs0 = *(const float4*)&Crd[wj * 32 + (l4 << 2)];
        float4 cs1 = *(const float4*)&Crd[wj * 32 + 16 + (l4 << 2)];
        float nc[2][4] = {{-cs0.x, -cs0.y, -cs0.z, -cs0.w},
                          {-cs1.x, -cs1.y, -cs1.z, -cs1.w}};
        bf16x8 af[2][4];
        #pragma unroll
        for (int m = 0; m < 2; ++m)
            #pragma unroll
            for (int ks = 0; ks < 4; ++ks)
                af[m][ks] = *(const bf16x8*)&Krd[(wj * 32 + m * 16 + l15) * 128
                                + ((((ks << 2) | l4) ^ (l15 & 7)) << 3)];
        __builtin_amdgcn_s_setprio(1);
        #pragma unroll
        for (int m = 0; m < 2; ++m)
            #pragma unroll
            for (int n = 0; n < 2; ++n) {
                f32x4 s = {};
                #pragma unroll
                for (int ks = 0; ks < 4; ++ks)
                    s = MFMA(af[m][ks], qf[n][ks], s);
                const int i = wi * 32 + n * 16 + l15;
                float p0 = exp2f(fmaf(s[0], SCALE_L2E, nc[m][0]));
                float p1 = exp2f(fmaf(s[1], SCALE_L2E, nc[m][1]));
                float p2 = exp2f(fmaf(s[2], SCALE_L2E, nc[m][2]));
                float p3 = exp2f(fmaf(s[3], SCALE_L2E, nc[m][3]));
                uint2 pp; pp.x = pk2(p0, p1); pp.y = pk2(p2, p3);
                const int c8 = wj * 4 + m * 2 + (l4 >> 1);
                *(uint2*)((char*)P + i * 128
                          + ((c8 ^ (i & 7)) << 4) + ((l4 & 1) << 3)) = pp;
            }
        __builtin_amdgcn_s_setprio(0);
    };
    auto phaseB = [&](const ushort* Vrd) {
        __builtin_amdgcn_s_setprio(1);
        #pragma unroll
        for (int ks = 0; ks < 2; ++ks) {
            bf16x8 va0 = *(const bf16x8*)&Vrd[(wv * 32 + l15) * 64
                            + ((((ks << 2) | l4) ^ (l15 & 7)) << 3)];
            bf16x8 va1 = *(const bf16x8*)&Vrd[(wv * 32 + 16 + l15) * 64
                            + ((((ks << 2) | l4) ^ (l15 & 7)) << 3)];
            #pragma unroll
            for (int n = 0; n < 4; ++n) {
                const int row = n * 16 + l15;
                const int c8 = ks * 4 + l4;
                bf16x8 pb = *(const bf16x8*)((const char*)P + row * 128
                                + ((c8 ^ (row & 7)) << 4));
                oacc[0][n] = MFMA(va0, pb, oacc[0][n]);
                oacc[1][n] = MFMA(va1, pb, oacc[1][n]);
            }
        }
        __builtin_amdgcn_s_setprio(0);
    };

    // tile: mode 0 = steady, 1 = t=NT-2, 2 = t=NT-1 (tail vmcnt ledger)
    auto tile = [&](int t, const ushort* Krd, const float* Crd, const ushort* Vrd,
                    ushort* Vwr, ushort* Kwr, float* Cwr, int mode) {
        if (mode < 2) asm volatile("s_waitcnt vmcnt(9)" ::: "memory");
        else          asm volatile("s_waitcnt vmcnt(4)" ::: "memory");
        __builtin_amdgcn_s_barrier();
        __builtin_amdgcn_sched_barrier(0);
        if (mode < 2) stageVt(Vwr, t + 1);
        phaseA(t, Krd, Crd);
        if (mode < 2) asm volatile("s_waitcnt vmcnt(9) lgkmcnt(0)" ::: "memory");
        else          asm volatile("s_waitcnt vmcnt(0) lgkmcnt(0)" ::: "memory");
        __builtin_amdgcn_s_barrier();
        __builtin_amdgcn_sched_barrier(0);
        if (mode == 0) { stageK(Kwr, t + 2); stageC(Cwr, t + 2); }
        phaseB(Vrd);
    };

    // prologue ledger: K0(4),C0(1),K1(4),C1(1),V0(4) = 14 items in flight
    stageK(K0, 0); stageC(C0, 0);
    stageK(K1, 1); stageC(C1, 1);
    stageVt(V0, 0);

    for (int t = 0; t < NT - 2; t += 2) {
        tile(t,     K0, C0, V0, V1, K0, C0, 0);
        tile(t + 1, K1, C1, V1, V0, K1, C1, 0);
    }
    tile(NT - 2, K0, C0, V0, V1, K0, C0, 1);   // issues V(15) only
    tile(NT - 1, K1, C1, V1, V0, K0, C0, 2);   // drains; no issues

    // epilogue: O^T[d][i] -> resb [b][i][h*128 + d]
    #pragma unroll
    for (int m = 0; m < 2; ++m)
        #pragma unroll
        for (int n = 0; n < 4; ++n) {
            const int i = i0 + n * 16 + l15;
            const int d = wv * 32 + m * 16 + (l4 << 2);
            uint2 p;
            p.x = pk2(oacc[m][n][0], oacc[m][n][1]);
            p.y = pk2(oacc[m][n][2], oacc[m][n][3]);
            *(uint2*)&resb[((size_t)b * SEQ + i) * (NH * DK) + h * DK + d] = p;
        }
}

// ---------------------------------------------------------------------------
// k4: out projection + bias + residual (double-buffered prefetch).
//   out[b][c][i] = sum_k Woutbf[c][k]*res[i][k] + bout[c] + x[b][c][i]
// ---------------------------------------------------------------------------
__global__ __launch_bounds__(256) void outproj_kernel(
    const ushort* __restrict__ resb, const ushort* __restrict__ woutbf,
    const float* __restrict__ bout, const float* __restrict__ x,
    float* __restrict__ out)
{
    __shared__ __attribute__((aligned(16))) ushort lds_a0[128 * 32];
    __shared__ __attribute__((aligned(16))) ushort lds_a1[128 * 32];
    __shared__ __attribute__((aligned(16))) ushort lds_b0[128 * 32];
    __shared__ __attribute__((aligned(16))) ushort lds_b1[128 * 32];
    const int tid = threadIdx.x;
    const int lane = tid & 63, wv = tid >> 6;
    const int l15 = lane & 15, l4 = lane >> 4;
    const int wm = wv >> 1, wn = wv & 1;
    const int swz = xcdswz(blockIdx.x, 512);
    const int i0 = (swz & 7) * 128;
    const int c0 = ((swz >> 3) & 3) * 128;
    const int b  = swz >> 5;

    auto stage = [&](int k0, ushort* la, ushort* lb) {
        #pragma unroll
        for (int l = 0; l < 2; ++l) {
            int chunk = l * 256 + tid;
            int row = chunk >> 2, c = chunk & 3;
            g2l16(&woutbf[(size_t)(c0 + row) * (NH * DK) + k0 + (c << 3)],
                  &la[(size_t)(l * 256 + wv * 64) * 8]);
        }
        #pragma unroll
        for (int l = 0; l < 2; ++l) {
            int chunk = l * 256 + tid;
            int row = chunk >> 2, c = chunk & 3;
            g2l16(&resb[((size_t)b * SEQ + i0 + row) * (NH * DK) + k0 + (c << 3)],
                  &lb[(size_t)(l * 256 + wv * 64) * 8]);
        }
    };

    f32x4 acc[4][4] = {};
    stage(0, lds_a0, lds_b0);
    __syncthreads();
    for (int it = 0; it < (NH * DK) / 32; ++it) {
        const ushort* la = (it & 1) ? lds_a1 : lds_a0;
        const ushort* lb = (it & 1) ? lds_b1 : lds_b0;
        if (it + 1 < (NH * DK) / 32)
            stage((it + 1) * 32, (it & 1) ? lds_a0 : lds_a1,
                                 (it & 1) ? lds_b0 : lds_b1);
        bf16x8 af[4], bfv[4];
        #pragma unroll
        for (int m = 0; m < 4; ++m)
            af[m] = *(const bf16x8*)&la[(wm * 64 + m * 16 + l15) * 32 + (l4 << 3)];
        #pragma unroll
        for (int n = 0; n < 4; ++n)
            bfv[n] = *(const bf16x8*)&lb[(wn * 64 + n * 16 + l15) * 32 + (l4 << 3)];
        #pragma unroll
        for (int m = 0; m < 4; ++m)
            #pragma unroll
            for (int n = 0; n < 4; ++n)
                acc[m][n] = MFMA(af[m], bfv[n], acc[m][n]);
        __syncthreads();
    }
    #pragma unroll
    for (int m = 0; m < 4; ++m) {
        const int cb = c0 + wm * 64 + m * 16 + (l4 << 2);
        float bia[4];
        #pragma unroll
        for (int r = 0; r < 4; ++r) bia[r] = bout[cb + r];
        #pragma unroll
        for (int n = 0; n < 4; ++n) {
            const int i = i0 + wn * 64 + n * 16 + l15;
            #pragma unroll
            for (int r = 0; r < 4; ++r) {
                size_t off = ((size_t)b * CIN + cb + r) * SEQ + i;
                out[off] = acc[m][n][r] + bia[r] + x[off];
            }
        }
    }
}

// ---------------------------------------------------------------------------
extern "C" void kernel_launch(void* const* d_in, const int* in_sizes, int n_in,
                              void* d_out, int out_size, void* d_ws, size_t ws_size,
                              hipStream_t stream) {
    const float* x      = (const float*)d_in[0];
    const float* w_proj = (const float*)d_in[1];
    const float* b_proj = (const float*)d_in[2];
    const float* w_out  = (const float*)d_in[3];
    const float* b_out  = (const float*)d_in[4];
    // n_heads (d_in[5]) hardcoded = 4

    const size_t xtE = (size_t)B_ * SEQ * CIN;        // bf16 elements
    const size_t qkE = (size_t)B_ * NH * SEQ * DK;    // bf16 elements
    ushort* xt    = (ushort*)d_ws;
    ushort* qb    = xt + xtE;
    ushort* kb    = qb + qkE;
    ushort* vtb   = kb + qkE;
    float*  cstat = (float*)(vtb + qkE);
    ushort* resb  = (ushort*)(cstat + 2 * (size_t)B_ * NH * SEQ);
    ushort* wobf  = resb + (size_t)B_ * SEQ * (NH * DK);
    // wpbf aliases resb: wpbf live only prep->qkv; resb written first in attn.
    ushort* wpbf  = resb;
    float*  out   = (float*)d_out;

    transpose_cast_kernel<<<dim3(SEQ / 64, CIN / 64, B_), 256, 0, stream>>>(x, xt);
    cast_kernel<<<dim3(1024), 256, 0, stream>>>(w_proj, w_out, wpbf, wobf);
    qkv_kernel<<<dim3(1536), 256, 0, stream>>>(wpbf, b_proj, xt, qb, kb, vtb);
    stats_kernel<<<dim3(512), 256, 0, stream>>>(qb, kb, cstat);
    attn_kernel<<<dim3(1024), 256, 0, stream>>>(qb, kb, vtb, cstat, resb);
    outproj_kernel<<<dim3(512), 256, 0, stream>>>(resb, wobf, b_out, x, out);
}

// Round 9
// 241.146 us; speedup vs baseline: 1.0130x; 1.0130x over previous
//
#include <hip/hip_runtime.h>
#include <hip/hip_bf16.h>
#include <math.h>

// Problem constants (fixed by setup_inputs)
#define B_    16
#define CIN   512
#define SEQ   1024
#define NH    4
#define DK    128
#define OUT3  1536
#define NT    16                      // j-tiles in attn (SEQ/64)
#define SCALE 0.08838834764831845f    // 1/sqrt(128)
// exp2-domain softmax: exp(s*SCALE - 8) == exp2(s*SCALE_L2E - CSHIFT_L2E)
#define SCALE_L2E  0.12751743360f     // SCALE * log2(e)
#define CSHIFT_L2E 11.54156032711f    // 8 * log2(e)

typedef __attribute__((ext_vector_type(8))) __bf16 bf16x8;   // MFMA A/B frag
typedef __attribute__((ext_vector_type(4))) float f32x4;     // MFMA C/D frag

#define MFMA(a, b, c) __builtin_amdgcn_mfma_f32_16x16x32_bf16((a), (b), (c), 0, 0, 0)

__device__ __forceinline__ ushort f2bf(float f) {
    __hip_bfloat16 h = __float2bfloat16(f);   // RTNE
    return *(ushort*)&h;
}
__device__ __forceinline__ uint pk2(float a, float b) {
    return (uint)f2bf(a) | ((uint)f2bf(b) << 16);
}
// async global->LDS, 16B per lane; lds dest is wave-uniform base (HW adds lane*16)
__device__ __forceinline__ void g2l16(const ushort* g, ushort* l) {
    __builtin_amdgcn_global_load_lds(
        (const __attribute__((address_space(1))) unsigned int*)g,
        (__attribute__((address_space(3))) unsigned int*)l, 16, 0, 0);
}
// T1: bijective XCD-chunked remap (nwg % 8 == 0 for all our grids)
__device__ __forceinline__ int xcdswz(int bid, int nwg) {
    return (bid & 7) * (nwg >> 3) + (bid >> 3);
}

// ---------------------------------------------------------------------------
// k0: x [B][C][seq] fp32 -> xt [B][seq][C] bf16  (LDS transpose, 64x64 tile)
// ---------------------------------------------------------------------------
__global__ __launch_bounds__(256) void transpose_cast_kernel(
    const float* __restrict__ x, ushort* __restrict__ xt)
{
    __shared__ ushort t[64 * 66];
    const int tid = threadIdx.x;
    const int i0 = blockIdx.x * 64, c0 = blockIdx.y * 64, b = blockIdx.z;

    #pragma unroll
    for (int l = 0; l < 4; ++l) {
        int idx = tid + l * 256;
        int c = idx >> 4, i4 = (idx & 15) << 2;
        float4 v = *(const float4*)&x[((size_t)b * CIN + c0 + c) * SEQ + i0 + i4];
        t[(i4 + 0) * 66 + c] = f2bf(v.x);
        t[(i4 + 1) * 66 + c] = f2bf(v.y);
        t[(i4 + 2) * 66 + c] = f2bf(v.z);
        t[(i4 + 3) * 66 + c] = f2bf(v.w);
    }
    __syncthreads();
    #pragma unroll
    for (int l = 0; l < 4; ++l) {
        int idx = tid + l * 256;
        int i = idx >> 4, c4 = (idx & 15) << 2;
        uint2 p;
        p.x = *(const uint*)&t[i * 66 + c4];
        p.y = *(const uint*)&t[i * 66 + c4 + 2];
        *(uint2*)&xt[((size_t)b * SEQ + i0 + i) * CIN + c0 + c4] = p;
    }
}

// ---------------------------------------------------------------------------
// prep: fp32 -> bf16 cast for BOTH w_proj (196608 quads) and w_out (65536)
// ---------------------------------------------------------------------------
__global__ __launch_bounds__(256) void cast_kernel(
    const float* __restrict__ wp, const float* __restrict__ wo,
    ushort* __restrict__ dwp, ushort* __restrict__ dwo)
{
    int idx = blockIdx.x * 256 + threadIdx.x;     // grid 1024 -> 262144 quads
    if (idx < 196608) {
        float4 v = *(const float4*)&wp[(size_t)idx * 4];
        uint2 p; p.x = pk2(v.x, v.y); p.y = pk2(v.z, v.w);
        *(uint2*)&dwp[(size_t)idx * 4] = p;
    } else {
        int j = idx - 196608;
        float4 v = *(const float4*)&wo[(size_t)j * 4];
        uint2 p; p.x = pk2(v.x, v.y); p.y = pk2(v.z, v.w);
        *(uint2*)&dwo[(size_t)j * 4] = p;
    }
}

// ---------------------------------------------------------------------------
// k1: QKV projection.  D[o][i] = sum_c Wbf[o][c] * xt[i][c]  (+bias)
// 128x128 block, BK=32, double-buffered global_load_lds prefetch-before-compute.
// q,k -> [bh][seq][128]; v -> TRANSPOSED [bh][128][seq].
// ---------------------------------------------------------------------------
__global__ __launch_bounds__(256) void qkv_kernel(
    const ushort* __restrict__ wbf, const float* __restrict__ bias,
    const ushort* __restrict__ xt,
    ushort* __restrict__ qb, ushort* __restrict__ kb, ushort* __restrict__ vtb)
{
    __shared__ __attribute__((aligned(16))) ushort lds_a0[128 * 32];
    __shared__ __attribute__((aligned(16))) ushort lds_a1[128 * 32];
    __shared__ __attribute__((aligned(16))) ushort lds_b0[128 * 32];
    __shared__ __attribute__((aligned(16))) ushort lds_b1[128 * 32];
    const int tid = threadIdx.x;
    const int lane = tid & 63, wv = tid >> 6;
    const int l15 = lane & 15, l4 = lane >> 4;
    const int wm = wv >> 1, wn = wv & 1;
    const int swz = xcdswz(blockIdx.x, 1536);
    const int o0 = (swz % 12) * 128;
    const int i0 = ((swz / 12) & 7) * 128;
    const int b  = swz / 96;

    auto stage = [&](int c0, ushort* la, ushort* lb) {
        #pragma unroll
        for (int l = 0; l < 2; ++l) {
            int chunk = l * 256 + tid;
            int row = chunk >> 2, c = chunk & 3;
            g2l16(&wbf[(size_t)(o0 + row) * CIN + c0 + (c << 3)],
                  &la[(size_t)(l * 256 + wv * 64) * 8]);
        }
        #pragma unroll
        for (int l = 0; l < 2; ++l) {
            int chunk = l * 256 + tid;
            int row = chunk >> 2, c = chunk & 3;
            g2l16(&xt[((size_t)b * SEQ + i0 + row) * CIN + c0 + (c << 3)],
                  &lb[(size_t)(l * 256 + wv * 64) * 8]);
        }
    };

    f32x4 acc[4][4] = {};
    stage(0, lds_a0, lds_b0);
    __syncthreads();
    for (int it = 0; it < CIN / 32; ++it) {
        const ushort* la = (it & 1) ? lds_a1 : lds_a0;
        const ushort* lb = (it & 1) ? lds_b1 : lds_b0;
        if (it + 1 < CIN / 32)
            stage((it + 1) * 32, (it & 1) ? lds_a0 : lds_a1,
                                 (it & 1) ? lds_b0 : lds_b1);
        bf16x8 af[4], bfv[4];
        #pragma unroll
        for (int m = 0; m < 4; ++m)
            af[m] = *(const bf16x8*)&la[(wm * 64 + m * 16 + l15) * 32 + (l4 << 3)];
        #pragma unroll
        for (int n = 0; n < 4; ++n)
            bfv[n] = *(const bf16x8*)&lb[(wn * 64 + n * 16 + l15) * 32 + (l4 << 3)];
        #pragma unroll
        for (int m = 0; m < 4; ++m)
            #pragma unroll
            for (int n = 0; n < 4; ++n)
                acc[m][n] = MFMA(af[m], bfv[n], acc[m][n]);
        __syncthreads();
    }
    // epilogue: o-block (128-aligned) sits in exactly one (head, q/k/v) chunk
    const int h = o0 / 384, which = (o0 % 384) / 128;
    const int bh = b * NH + h;
    #pragma unroll
    for (int m = 0; m < 4; ++m) {
        const int d0 = wm * 64 + m * 16 + (l4 << 2);
        float bia[4];
        #pragma unroll
        for (int r = 0; r < 4; ++r) bia[r] = bias[o0 + d0 + r];
        #pragma unroll
        for (int n = 0; n < 4; ++n) {
            const int i = i0 + wn * 64 + n * 16 + l15;
            float v0 = acc[m][n][0] + bia[0], v1 = acc[m][n][1] + bia[1];
            float v2 = acc[m][n][2] + bia[2], v3 = acc[m][n][3] + bia[3];
            if (which == 2) {                     // v: transposed store [bh][d][i]
                vtb[((size_t)bh * DK + d0 + 0) * SEQ + i] = f2bf(v0);
                vtb[((size_t)bh * DK + d0 + 1) * SEQ + i] = f2bf(v1);
                vtb[((size_t)bh * DK + d0 + 2) * SEQ + i] = f2bf(v2);
                vtb[((size_t)bh * DK + d0 + 3) * SEQ + i] = f2bf(v3);
            } else {                              // q/k: [bh][i][d], 8B packed
                ushort* dst = (which == 0) ? qb : kb;
                uint2 p; p.x = pk2(v0, v1); p.y = pk2(v2, v3);
                *(uint2*)&dst[((size_t)bh * SEQ + i) * DK + d0] = p;
            }
        }
    }
}

// ---------------------------------------------------------------------------
// k2: column-softmax stats via S^T = K * Q^T  (softmax axis i in lane dim).
// exp2-domain fixed shift: cstat[j] = CSHIFT_L2E + log2(sum_i 2^(s*SCALE_L2E
// - CSHIFT_L2E)).  attn then computes P = 2^(s*SCALE_L2E - cstat) exactly.
// ---------------------------------------------------------------------------
__global__ __launch_bounds__(256) void stats_kernel(
    const ushort* __restrict__ qb, const ushort* __restrict__ kb,
    float* __restrict__ cstat)
{
    __shared__ __attribute__((aligned(16))) ushort lds_q0[64 * 128];
    __shared__ __attribute__((aligned(16))) ushort lds_q1[64 * 128];
    const int tid = threadIdx.x;
    const int lane = tid & 63, wv = tid >> 6;
    const int l15 = lane & 15, l4 = lane >> 4;
    const int swz = xcdswz(blockIdx.x, 512);
    const int bh = swz >> 3;
    const int j0 = (swz & 7) * 128 + wv * 32;
    const ushort* kbase = kb + (size_t)bh * SEQ * DK;
    const ushort* qbase = qb + (size_t)bh * SEQ * DK;

    auto stageQ = [&](int it, ushort* dst) {
        #pragma unroll
        for (int l = 0; l < 4; ++l) {
            int chunk = l * 256 + tid;
            int row = chunk >> 4, c = chunk & 15;
            g2l16(&qbase[(size_t)(it * 64 + row) * DK + ((c ^ (row & 7)) << 3)],
                  &dst[(size_t)(l * 256 + wv * 64) * 8]);
        }
    };

    bf16x8 kf[2][4];                      // wave's K rows [j32][128] in regs
    #pragma unroll
    for (int m = 0; m < 2; ++m)
        #pragma unroll
        for (int ks = 0; ks < 4; ++ks)
            kf[m][ks] = *(const bf16x8*)&kbase[(size_t)(j0 + m * 16 + l15) * DK
                                               + ks * 32 + (l4 << 3)];
    float ss[2][4] = {};

    stageQ(0, lds_q0);
    __syncthreads();
    for (int it = 0; it < SEQ / 64; ++it) {
        const ushort* lq = (it & 1) ? lds_q1 : lds_q0;
        if (it + 1 < SEQ / 64)
            stageQ(it + 1, (it & 1) ? lds_q0 : lds_q1);
        f32x4 sa0[4], sa1[4];
        __builtin_amdgcn_s_setprio(1);
        #pragma unroll
        for (int n = 0; n < 4; ++n) {
            f32x4 a0 = {}, a1 = {};
            #pragma unroll
            for (int ks = 0; ks < 4; ++ks) {
                bf16x8 bq = *(const bf16x8*)&lq[(n * 16 + l15) * 128
                                + ((((ks << 2) | l4) ^ (l15 & 7)) << 3)];
                a0 = MFMA(kf[0][ks], bq, a0);
                a1 = MFMA(kf[1][ks], bq, a1);
            }
            sa0[n] = a0; sa1[n] = a1;
        }
        __builtin_amdgcn_s_setprio(0);
        #pragma unroll
        for (int r = 0; r < 4; ++r) {
            float e0 = 0.0f, e1 = 0.0f;
            #pragma unroll
            for (int n = 0; n < 4; ++n) {
                e0 += exp2f(fmaf(sa0[n][r], SCALE_L2E, -CSHIFT_L2E));
                e1 += exp2f(fmaf(sa1[n][r], SCALE_L2E, -CSHIFT_L2E));
            }
            ss[0][r] += e0;
            ss[1][r] += e1;
        }
        __syncthreads();
    }
    #pragma unroll
    for (int m = 0; m < 2; ++m)
        #pragma unroll
        for (int r = 0; r < 4; ++r) {
            float sv = ss[m][r];
            #pragma unroll
            for (int wmask = 1; wmask < 16; wmask <<= 1)
                sv += __shfl_xor(sv, wmask, 64);
            if (l15 == 0) {
                int j = j0 + m * 16 + (l4 << 2) + r;
                cstat[(size_t)bh * SEQ + j] = CSHIFT_L2E + __log2f(sv);
            }
        }
}

// ---------------------------------------------------------------------------
// k3: attention output — i-tile 128 (fixed per-tile overhead amortized over
// 2x MFMA).  r7 sync skeleton: 2 __syncthreads per j-tile.  Per j-tile:
//   stage Vt(t) ; phase A: S^T=K*Q^T (K from LDS, Q[i128] in regs),
//   P[i128][j64] -> swizzled LDS ; sync ; stage K(t+1) ;
//   phase B: O^T[d128][i128] += V^T * P^T ; sync.
// ---------------------------------------------------------------------------
__global__ __launch_bounds__(256) void attn_kernel(
    const ushort* __restrict__ qb, const ushort* __restrict__ kb,
    const ushort* __restrict__ vtb, const float* __restrict__ cstat,
    ushort* __restrict__ resb)
{
    __shared__ __attribute__((aligned(16))) ushort lds_k[64 * 128];   // [j][d] swz
    __shared__ __attribute__((aligned(16))) ushort lds_vt[128 * 64];  // [d][j] swz
    __shared__ __attribute__((aligned(16))) ushort lds_p[128 * 64];   // [i][j] swz16B
    const int tid = threadIdx.x;
    const int lane = tid & 63, wv = tid >> 6;
    const int l15 = lane & 15, l4 = lane >> 4;
    const int wj = wv & 1, wi = wv >> 1;
    const int swz = xcdswz(blockIdx.x, 512);
    const int bh = swz >> 3, b = bh >> 2, h = bh & 3;
    const int i0 = (swz & 7) * 128;
    const ushort* qbase = qb + (size_t)bh * SEQ * DK;
    const ushort* kbase = kb + (size_t)bh * SEQ * DK;
    const ushort* vtbase = vtb + (size_t)bh * DK * SEQ;
    const float* cbase = cstat + (size_t)bh * SEQ;

    auto stageK = [&](int j0t) {
        #pragma unroll
        for (int l = 0; l < 4; ++l) {
            int chunk = l * 256 + tid;
            int row = chunk >> 4, c = chunk & 15;
            g2l16(&kbase[(size_t)(j0t + row) * DK + ((c ^ (row & 7)) << 3)],
                  &lds_k[(size_t)(l * 256 + wv * 64) * 8]);
        }
    };
    auto stageVt = [&](int j0t) {
        #pragma unroll
        for (int l = 0; l < 4; ++l) {
            int chunk = l * 256 + tid;
            int row = chunk >> 3, c = chunk & 7;
            g2l16(&vtbase[(size_t)row * SEQ + j0t + ((c ^ (row & 7)) << 3)],
                  &lds_vt[(size_t)(l * 256 + wv * 64) * 8]);
        }
    };

    bf16x8 qf[4][4];                      // wave's Q rows [i64 half][128] in regs
    #pragma unroll
    for (int n = 0; n < 4; ++n)
        #pragma unroll
        for (int ks = 0; ks < 4; ++ks)
            qf[n][ks] = *(const bf16x8*)&qbase[(size_t)(i0 + wi * 64 + n * 16 + l15) * DK
                                               + ks * 32 + (l4 << 3)];
    f32x4 oacc[2][8] = {};                // [d16-sub within wv*32][i16-sub of 128]

    stageK(0);
    __syncthreads();
    for (int jt = 0; jt < NT; ++jt) {
        const int j0 = jt * 64;
        stageVt(j0);                               // needed only in phase B
        float4 cs0 = *(const float4*)&cbase[j0 + wj * 32 + (l4 << 2)];
        float4 cs1 = *(const float4*)&cbase[j0 + wj * 32 + 16 + (l4 << 2)];
        float nc[2][4] = {{-cs0.x, -cs0.y, -cs0.z, -cs0.w},
                          {-cs1.x, -cs1.y, -cs1.z, -cs1.w}};
        // ---- phase A: wave tile j32 (wj) x i64 (wi) ----
        bf16x8 af[2][4];
        #pragma unroll
        for (int m = 0; m < 2; ++m)
            #pragma unroll
            for (int ks = 0; ks < 4; ++ks)
                af[m][ks] = *(const bf16x8*)&lds_k[(wj * 32 + m * 16 + l15) * 128
                                + ((((ks << 2) | l4) ^ (l15 & 7)) << 3)];
        __builtin_amdgcn_s_setprio(1);
        #pragma unroll
        for (int m = 0; m < 2; ++m)
            #pragma unroll
            for (int n = 0; n < 4; ++n) {
                f32x4 s = {};
                #pragma unroll
                for (int ks = 0; ks < 4; ++ks)
                    s = MFMA(af[m][ks], qf[n][ks], s);
                const int i = wi * 64 + n * 16 + l15;
                float p0 = exp2f(fmaf(s[0], SCALE_L2E, nc[m][0]));
                float p1 = exp2f(fmaf(s[1], SCALE_L2E, nc[m][1]));
                float p2 = exp2f(fmaf(s[2], SCALE_L2E, nc[m][2]));
                float p3 = exp2f(fmaf(s[3], SCALE_L2E, nc[m][3]));
                uint2 pp; pp.x = pk2(p0, p1); pp.y = pk2(p2, p3);
                const int c8 = wj * 4 + m * 2 + (l4 >> 1);
                *(uint2*)((char*)lds_p + i * 128
                          + ((c8 ^ (i & 7)) << 4) + ((l4 & 1) << 3)) = pp;
            }
        __builtin_amdgcn_s_setprio(0);
        __syncthreads();                           // Vt(t) ready; lds_k free; P visible
        if (jt + 1 < NT) stageK(j0 + 64);          // prefetch under phase B
        // ---- phase B: wave owns d32 = wv*32, all i128 ----
        __builtin_amdgcn_s_setprio(1);
        #pragma unroll
        for (int ks = 0; ks < 2; ++ks) {
            bf16x8 va0 = *(const bf16x8*)&lds_vt[(wv * 32 + l15) * 64
                            + ((((ks << 2) | l4) ^ (l15 & 7)) << 3)];
            bf16x8 va1 = *(const bf16x8*)&lds_vt[(wv * 32 + 16 + l15) * 64
                            + ((((ks << 2) | l4) ^ (l15 & 7)) << 3)];
            #pragma unroll
            for (int n = 0; n < 8; ++n) {
                const int row = n * 16 + l15;
                const int c8 = ks * 4 + l4;
                bf16x8 pb = *(const bf16x8*)((const char*)lds_p + row * 128
                                + ((c8 ^ (row & 7)) << 4));
                oacc[0][n] = MFMA(va0, pb, oacc[0][n]);
                oacc[1][n] = MFMA(va1, pb, oacc[1][n]);
            }
        }
        __builtin_amdgcn_s_setprio(0);
        __syncthreads();                           // K(t+1) ready; lds_vt/lds_p free
    }
    // epilogue: O^T[d][i] -> resb [b][i][h*128 + d]
    #pragma unroll
    for (int m = 0; m < 2; ++m)
        #pragma unroll
        for (int n = 0; n < 8; ++n) {
            const int i = i0 + n * 16 + l15;
            const int d = wv * 32 + m * 16 + (l4 << 2);
            uint2 p;
            p.x = pk2(oacc[m][n][0], oacc[m][n][1]);
            p.y = pk2(oacc[m][n][2], oacc[m][n][3]);
            *(uint2*)&resb[((size_t)b * SEQ + i) * (NH * DK) + h * DK + d] = p;
        }
}

// ---------------------------------------------------------------------------
// k4: out projection + bias + residual (double-buffered prefetch).
//   out[b][c][i] = sum_k Woutbf[c][k]*res[i][k] + bout[c] + x[b][c][i]
// ---------------------------------------------------------------------------
__global__ __launch_bounds__(256) void outproj_kernel(
    const ushort* __restrict__ resb, const ushort* __restrict__ woutbf,
    const float* __restrict__ bout, const float* __restrict__ x,
    float* __restrict__ out)
{
    __shared__ __attribute__((aligned(16))) ushort lds_a0[128 * 32];
    __shared__ __attribute__((aligned(16))) ushort lds_a1[128 * 32];
    __shared__ __attribute__((aligned(16))) ushort lds_b0[128 * 32];
    __shared__ __attribute__((aligned(16))) ushort lds_b1[128 * 32];
    const int tid = threadIdx.x;
    const int lane = tid & 63, wv = tid >> 6;
    const int l15 = lane & 15, l4 = lane >> 4;
    const int wm = wv >> 1, wn = wv & 1;
    const int swz = xcdswz(blockIdx.x, 512);
    const int i0 = (swz & 7) * 128;
    const int c0 = ((swz >> 3) & 3) * 128;
    const int b  = swz >> 5;

    auto stage = [&](int k0, ushort* la, ushort* lb) {
        #pragma unroll
        for (int l = 0; l < 2; ++l) {
            int chunk = l * 256 + tid;
            int row = chunk >> 2, c = chunk & 3;
            g2l16(&woutbf[(size_t)(c0 + row) * (NH * DK) + k0 + (c << 3)],
                  &la[(size_t)(l * 256 + wv * 64) * 8]);
        }
        #pragma unroll
        for (int l = 0; l < 2; ++l) {
            int chunk = l * 256 + tid;
            int row = chunk >> 2, c = chunk & 3;
            g2l16(&resb[((size_t)b * SEQ + i0 + row) * (NH * DK) + k0 + (c << 3)],
                  &lb[(size_t)(l * 256 + wv * 64) * 8]);
        }
    };

    f32x4 acc[4][4] = {};
    stage(0, lds_a0, lds_b0);
    __syncthreads();
    for (int it = 0; it < (NH * DK) / 32; ++it) {
        const ushort* la = (it & 1) ? lds_a1 : lds_a0;
        const ushort* lb = (it & 1) ? lds_b1 : lds_b0;
        if (it + 1 < (NH * DK) / 32)
            stage((it + 1) * 32, (it & 1) ? lds_a0 : lds_a1,
                                 (it & 1) ? lds_b0 : lds_b1);
        bf16x8 af[4], bfv[4];
        #pragma unroll
        for (int m = 0; m < 4; ++m)
            af[m] = *(const bf16x8*)&la[(wm * 64 + m * 16 + l15) * 32 + (l4 << 3)];
        #pragma unroll
        for (int n = 0; n < 4; ++n)
            bfv[n] = *(const bf16x8*)&lb[(wn * 64 + n * 16 + l15) * 32 + (l4 << 3)];
        #pragma unroll
        for (int m = 0; m < 4; ++m)
            #pragma unroll
            for (int n = 0; n < 4; ++n)
                acc[m][n] = MFMA(af[m], bfv[n], acc[m][n]);
        __syncthreads();
    }
    #pragma unroll
    for (int m = 0; m < 4; ++m) {
        const int cb = c0 + wm * 64 + m * 16 + (l4 << 2);
        float bia[4];
        #pragma unroll
        for (int r = 0; r < 4; ++r) bia[r] = bout[cb + r];
        #pragma unroll
        for (int n = 0; n < 4; ++n) {
            const int i = i0 + wn * 64 + n * 16 + l15;
            #pragma unroll
            for (int r = 0; r < 4; ++r) {
                size_t off = ((size_t)b * CIN + cb + r) * SEQ + i;
                out[off] = acc[m][n][r] + bia[r] + x[off];
            }
        }
    }
}

// ---------------------------------------------------------------------------
extern "C" void kernel_launch(void* const* d_in, const int* in_sizes, int n_in,
                              void* d_out, int out_size, void* d_ws, size_t ws_size,
                              hipStream_t stream) {
    const float* x      = (const float*)d_in[0];
    const float* w_proj = (const float*)d_in[1];
    const float* b_proj = (const float*)d_in[2];
    const float* w_out  = (const float*)d_in[3];
    const float* b_out  = (const float*)d_in[4];
    // n_heads (d_in[5]) hardcoded = 4

    const size_t xtE = (size_t)B_ * SEQ * CIN;        // bf16 elements
    const size_t qkE = (size_t)B_ * NH * SEQ * DK;    // bf16 elements
    ushort* xt    = (ushort*)d_ws;
    ushort* qb    = xt + xtE;
    ushort* kb    = qb + qkE;
    ushort* vtb   = kb + qkE;
    float*  cstat = (float*)(vtb + qkE);
    ushort* resb  = (ushort*)(cstat + 2 * (size_t)B_ * NH * SEQ);
    ushort* wobf  = resb + (size_t)B_ * SEQ * (NH * DK);
    // wpbf aliases resb: wpbf live only prep->qkv; resb written first in attn.
    ushort* wpbf  = resb;
    float*  out   = (float*)d_out;

    transpose_cast_kernel<<<dim3(SEQ / 64, CIN / 64, B_), 256, 0, stream>>>(x, xt);
    cast_kernel<<<dim3(1024), 256, 0, stream>>>(w_proj, w_out, wpbf, wobf);
    qkv_kernel<<<dim3(1536), 256, 0, stream>>>(wpbf, b_proj, xt, qb, kb, vtb);
    stats_kernel<<<dim3(512), 256, 0, stream>>>(qb, kb, cstat);
    attn_kernel<<<dim3(512), 256, 0, stream>>>(qb, kb, vtb, cstat, resb);
    outproj_kernel<<<dim3(512), 256, 0, stream>>>(resb, wobf, b_out, x, out);
}